// Round 4
// baseline (627.155 us; speedup 1.0000x reference)
//
#include <hip/hip_runtime.h>
#include <stdint.h>

// ============================================================================
// CTSimFBOnlyGLM — bit-exact replication of the JAX reference (XLA:CPU
// semantics) including the threefry2x32 PRNG chain.
//
// Validated R1-R3 (absmax 0.0): threefry-partitionable RNG; sequential-p
// spatial proj (mul+add); Eigen predux8 conv; ascending-k gated feedback;
// logit-threshold fast path with band -> exact ladder slow path.
//
// R4 (perf only; decisions provably identical):
//  * k_sim: 2-step speculative decision — one ballot round-trip per 2 steps.
//    dlt  = vgt + r0            (step i decision = bit i)
//    dlt1 = dlt + f249          (step i+1 decision if spike_i=1 = bit i+1)
//    Step i's scatter applies fl(r0+f249) at lane i+1 BEFORE step i+1's
//    slow path reads it => exact ascending-k order preserved. Fast-path
//    reassociation error ~1e-9 << 1.5e-5 band slack.
//  * k_sim: coefficients register-prefetched distance-2 rounds (4-slot ring,
//    unroll 4) — LDS latency off the critical path.
//  * k_sp: p-rows streamed through LDS ring via global_load_lds (48 loads
//    in flight/wave, explicit s_waitcnt vmcnt) — accumulation order unchanged.
// ============================================================================

#pragma clang fp contract(off)

#define TF_ROUND(r) do { x0 += x1; x1 = (x1 << (r)) | (x1 >> (32 - (r))); x1 ^= x0; } while (0)

__device__ __forceinline__ void tf2x32(uint32_t k0, uint32_t k1,
                                       uint32_t x0, uint32_t x1,
                                       uint32_t& o0, uint32_t& o1) {
  const uint32_t k2 = k0 ^ k1 ^ 0x1BD11BDAu;
  x0 += k0; x1 += k1;
  TF_ROUND(13); TF_ROUND(15); TF_ROUND(26); TF_ROUND(6);
  x0 += k1; x1 += k2 + 1u;
  TF_ROUND(17); TF_ROUND(29); TF_ROUND(16); TF_ROUND(24);
  x0 += k2; x1 += k0 + 2u;
  TF_ROUND(13); TF_ROUND(15); TF_ROUND(26); TF_ROUND(6);
  x0 += k0; x1 += k1 + 3u;
  TF_ROUND(17); TF_ROUND(29); TF_ROUND(16); TF_ROUND(24);
  x0 += k1; x1 += k2 + 4u;
  TF_ROUND(13); TF_ROUND(15); TF_ROUND(26); TF_ROUND(6);
  x0 += k2; x1 += k0 + 5u;
  o0 = x0; o1 = x1;
}

// Cephes/Eigen-style f32 exp as XLA's GenerateVF32Exp emits it.
__device__ __forceinline__ float xla_exp_f32(float x) {
  #pragma clang fp contract(off)
  x = fminf(x, 88.3762626647950f);
  x = fmaxf(x, -88.3762626647949f);
  float fx = x * 1.44269504088896341f + 0.5f;
  fx = floorf(fx);
  const float tmp = fx * 0.693359375f;
  const float z0  = fx * (-2.12194440e-4f);
  x = x - tmp;
  x = x - z0;
  const float zz = x * x;
  float y = 1.9875691500e-4f;
  y = y * x + 1.3981999507e-3f;
  y = y * x + 8.3334519073e-3f;
  y = y * x + 4.1665795894e-2f;
  y = y * x + 1.6666665459e-1f;
  y = y * x + 5.0000001201e-1f;
  y = y * zz + x;
  y = y + 1.0f;
  const int n = (int)fx;
  const float p2n = __uint_as_float((uint32_t)(n + 127) << 23);
  return y * p2n;
}

__device__ __forceinline__ float xla_sigmoid_f32(float x) {
  #pragma clang fp contract(off)
  const float e = xla_exp_f32(-x);
  return 1.0f / (1.0f + e);
}

__device__ __forceinline__ float rl_f(float v, int i) {
  return __uint_as_float((uint32_t)__builtin_amdgcn_readlane((int)__float_as_uint(v), i));
}

// Exact reference decision ladder (R1-validated). x = fl(g + fb).
__device__ __forceinline__ uint32_t ladder(float x, float u) {
  #pragma clang fp contract(off)
  const float ef = __expf(-x);
  const float rf = __builtin_amdgcn_rcpf(1.0f + ef);
  const float d2 = u - rf;
  if (fabsf(d2) > 2e-6f) return (d2 < 0.f) ? 1u : 0u;
  const double sd = 1.0 / (1.0 + exp(-(double)x));
  const double dd = (double)u - sd;
  if (fabs(dd) > 5e-7) return (dd < 0.0) ? 1u : 0u;
  return (u < xla_sigmoid_f32(x)) ? 1u : 0u;
}

// ---------------------------------------------------------------------------
// Kernel 1: sp[b,t] = sum_p w[p]*stim[b,p,t]   (sequential p, mul+add).
// p-rows (256 B each, 64 lanes x 4 B) streamed into an LDS ring of 4x16 rows
// via async global_load_lds; 48 loads kept in flight per wave with explicit
// s_waitcnt vmcnt. Accumulation strictly ascending p (order-validated).
// ---------------------------------------------------------------------------
__global__ __launch_bounds__(64) void k_sp(const float* __restrict__ stim,
                                           const float* __restrict__ w,
                                           float* __restrict__ sp) {
  #pragma clang fp contract(off)
  __shared__ float w_lds[2048];
  __shared__ float buf[4][16][64];          // 16 KB ring, slot = chunk & 3
  const int lane = threadIdx.x;
  const int blk  = blockIdx.x;              // 0..255
  const int b  = blk >> 6;
  const int t0 = (blk & 63) * 64;           // wave-uniform t base
  for (int j = lane; j < 2048; j += 64) w_lds[j] = w[j];
  __syncthreads();

  const float* __restrict__ gbase = stim + (size_t)b * (2048u * 4096u) + t0;

  // Issue one 16-row chunk (p = c*16 .. c*16+15) into ring slot c&3.
  #define ISSUE_CHUNK(c)                                                      \
    do {                                                                      \
      const int _s = (c) & 3;                                                 \
      _Pragma("unroll")                                                       \
      for (int _k = 0; _k < 16; ++_k) {                                       \
        const float* _gp = gbase + (size_t)((c) * 16 + _k) * 4096 + lane;     \
        __builtin_amdgcn_global_load_lds(                                     \
            (const __attribute__((address_space(1))) void*)_gp,               \
            (__attribute__((address_space(3))) void*)&buf[_s][_k][0],         \
            4, 0, 0);                                                         \
      }                                                                       \
    } while (0)

  ISSUE_CHUNK(0); ISSUE_CHUNK(1); ISSUE_CHUNK(2);

  float acc = 0.f;
  for (int c = 0; c < 126; ++c) {
    asm volatile("s_waitcnt vmcnt(32)" ::: "memory");   // chunk c landed
    if (c + 3 < 128) ISSUE_CHUNK(c + 3);
    const int slot = c & 3;
    const float* __restrict__ wl = &w_lds[c * 16];
    #pragma unroll
    for (int k = 0; k < 16; ++k) acc = acc + wl[k] * buf[slot][k][lane];
  }
  asm volatile("s_waitcnt vmcnt(16)" ::: "memory");
  {
    const float* __restrict__ wl = &w_lds[126 * 16];
    #pragma unroll
    for (int k = 0; k < 16; ++k) acc = acc + wl[k] * buf[2][k][lane];
  }
  asm volatile("s_waitcnt vmcnt(0)" ::: "memory");
  {
    const float* __restrict__ wl = &w_lds[127 * 16];
    #pragma unroll
    for (int k = 0; k < 16; ++k) acc = acc + wl[k] * buf[3][k][lane];
  }
  sp[blk * 64 + lane] = acc;
  #undef ISSUE_CHUNK
}

// ---------------------------------------------------------------------------
// Kernel 2: gensig[b,l] = conv_valid(sp, tc)[b,l] + bias
// Eigen RowMajor gemv model: 8 partials (mul+add), predux8 tree, 2 tails.
// ---------------------------------------------------------------------------
__global__ __launch_bounds__(64) void k_conv(const float* __restrict__ sp,
                                             const float* __restrict__ tc,
                                             const float* __restrict__ bias,
                                             float* __restrict__ gensig) {
  #pragma clang fp contract(off)
  const int tid = blockIdx.x * 64 + threadIdx.x;
  if (tid >= 4 * 3847) return;
  const int b = tid / 3847;
  const int l = tid - b * 3847;
  const float* __restrict__ s = sp + b * 4096 + l;
  float a[8];
  #pragma unroll
  for (int j = 0; j < 8; ++j) a[j] = 0.f;
  for (int c = 0; c < 31; ++c) {
    const int k = c * 8;
    #pragma unroll
    for (int j = 0; j < 8; ++j) a[j] = a[j] + s[k + j] * tc[k + j];
  }
  const float b0 = a[0] + a[4];
  const float b1 = a[1] + a[5];
  const float b2 = a[2] + a[6];
  const float b3 = a[3] + a[7];
  float cc = (b0 + b2) + (b1 + b3);
  cc = cc + s[248] * tc[248];
  cc = cc + s[249] * tc[249];
  gensig[tid] = cc + bias[0];
}

// ---------------------------------------------------------------------------
// Kernel 3: sequential simulation, one wave per trajectory, ring in VGPRs,
// 2-step speculative decisions, distance-2 coefficient prefetch.
// ---------------------------------------------------------------------------
__global__ __launch_bounds__(64) void k_sim(const float* __restrict__ gensig,
                                            const float* __restrict__ init,
                                            const float* __restrict__ fbf,
                                            float* __restrict__ out) {
  #pragma clang fp contract(off)
  __shared__ float ring[256];
  __shared__ float f_lds[256];
  __shared__ float init_lds[256];
  __shared__ float T[512];
  const int lane = threadIdx.x;
  const int traj = blockIdx.x;        // b*64 + r, flat (4,64) index
  const int b = traj >> 6;

  for (int j = lane; j < 256; j += 64) {
    f_lds[j]    = (j < 250) ? fbf[j] : 0.f;
    init_lds[j] = (j < 250) ? init[b * 250 + j] : 0.f;
    ring[j] = 0.f;
  }
  __syncthreads();

  // Coefficient tables (R3-validated mapping).
  for (int idx = lane; idx < 512; idx += 64) {
    const int j = idx >> 7;
    const int e = (idx & 127) - 64;
    int src;
    if (j == 0) src = (e < 0) ? (250 + e) : (e - 6);
    else        src = 250 - 64 * j + e;
    T[idx] = (src >= 0 && src < 250) ? f_lds[src] : 0.f;
  }

  // Initial-window ring: slot s = sum_{k=0..249-s} init[s+k]*f[k], asc. k.
  for (int s = lane; s < 250; s += 64) {
    float acc = 0.f;
    const int kmax = 249 - s;
    for (int k = 0; k <= kmax; ++k) acc = acc + init_lds[s + k] * f_lds[k];
    ring[s] = acc;
  }
  __syncthreads();

  const size_t ob = (size_t)traj * 4096;
  for (int j = lane; j < 250; j += 64) out[ob + j] = init_lds[j];

  float r0 = ring[lane];
  float r1 = ring[lane + 64];
  float r2 = ring[lane + 128];
  float r3 = ring[lane + 192];

  const float* __restrict__ grow = gensig + b * 3847;
  const float* __restrict__ Tl = &T[64 - lane];
  const float f249 = f_lds[249];

  // Coefficient prefetch ring: slot q holds round (…)'s 8 coefs
  // (steps 2q,2q+1): [0..3] = step A's a0..a3, [4..7] = step B's.
  float pf[4][8];
  #pragma unroll
  for (int q = 0; q < 2; ++q) {
    #pragma unroll
    for (int j = 0; j < 4; ++j) {
      pf[q][j]     = Tl[2 * q + 128 * j];
      pf[q][4 + j] = Tl[2 * q + 1 + 128 * j];
    }
  }

  for (int tb = 0; tb < 3904; tb += 64) {     // 61 chunks; last one padded
    const int tl = tb + lane;
    float vg = 0.f, vu = 0.f, vgt, band;
    if (tl < 3846) {
      vg = grow[tl];
      uint32_t a0, a1, c0, c1;
      tf2x32(0u, 42u, 0u, (uint32_t)tl, a0, a1);      // keys[t] (fold-like split)
      tf2x32(a0, a1, 0u, (uint32_t)traj, c0, c1);     // per-step bits, elem m=traj
      const uint32_t bits = c0 ^ c1;
      vu = __uint_as_float((bits >> 9) | 0x3f800000u) - 1.0f;
      const float om = 1.0f - vu;                     // exact (u has <=23 bits)
      const float th = __log2f(vu / om) * 0.69314718055994531f;
      vgt = vg - th;
      band = 1.5e-5f + 2e-6f / om
           + 3e-7f * (fabsf(th) + fabsf(vg) + fabsf(vgt));
    } else {
      vgt = -INFINITY;                                // padded: never spikes
      band = -1.0f;                                   // and never goes slow
    }
    uint64_t smask = 0;
    #pragma unroll 4
    for (int r = 0; r < 32; ++r) {
      const int q = r & 3;
      // prefetch round r+2 (wraps to next chunk's identical table)
      {
        const int s2 = (r + 2) & 3;
        const int ip = 2 * ((r + 2) & 31);
        #pragma unroll
        for (int j = 0; j < 4; ++j) {
          pf[s2][j]     = Tl[ip + 128 * j];
          pf[s2][4 + j] = Tl[ip + 1 + 128 * j];
        }
      }
      const int i = 2 * r;
      const float dlt  = vgt + r0;
      const float dlt1 = dlt + f249;
      const uint64_t ms0 = __ballot(dlt  > 0.0f);
      const uint64_t ms1 = __ballot(dlt1 > 0.0f);
      const uint64_t mb0 = __ballot(fabsf(dlt)  <= band);
      const uint64_t mb1 = __ballot(fabsf(dlt1) <= band);

      // --- step i ---
      uint32_t sA = (uint32_t)(ms0 >> i) & 1u;
      if (__builtin_expect((int)((mb0 >> i) & 1ull), 0)) {
        const float x = rl_f(vg, i) + rl_f(r0, i);    // pre-retire r0
        sA = ladder(x, rl_f(vu, i));
      }
      const float sfA = sA ? 1.0f : 0.0f;
      r0 = (lane == i) ? 0.0f : r0;                   // retire slot i
      r0 = __builtin_fmaf(sfA, pf[q][0], r0);         // lane i+1 gets f249
      r1 = __builtin_fmaf(sfA, pf[q][1], r1);
      r2 = __builtin_fmaf(sfA, pf[q][2], r2);
      r3 = __builtin_fmaf(sfA, pf[q][3], r3);

      // --- step i+1 (speculatively decided) ---
      const uint64_t msel = sA ? ms1 : ms0;
      const uint64_t bsel = sA ? mb1 : mb0;
      uint32_t sB = (uint32_t)(msel >> (i + 1)) & 1u;
      if (__builtin_expect((int)((bsel >> (i + 1)) & 1ull), 0)) {
        // r0 at lane i+1 is now physically fl(r0_pre [+ f249]) — exact.
        const float x = rl_f(vg, i + 1) + rl_f(r0, i + 1);
        sB = ladder(x, rl_f(vu, i + 1));
      }
      const float sfB = sB ? 1.0f : 0.0f;
      r0 = (lane == i + 1) ? 0.0f : r0;               // retire slot i+1
      r0 = __builtin_fmaf(sfB, pf[q][4], r0);
      r1 = __builtin_fmaf(sfB, pf[q][5], r1);
      r2 = __builtin_fmaf(sfB, pf[q][6], r2);
      r3 = __builtin_fmaf(sfB, pf[q][7], r3);

      smask |= ((uint64_t)sA) << i;
      smask |= ((uint64_t)sB) << (i + 1);
    }
    if (tl < 3846) out[ob + 250 + tl] = (float)((smask >> lane) & 1ull);
    // rotate ring registers for the next 64-step chunk
    const float tmp = r0; r0 = r1; r1 = r2; r2 = r3; r3 = tmp;
  }
}

// ---------------------------------------------------------------------------
extern "C" void kernel_launch(void* const* d_in, const int* in_sizes, int n_in,
                              void* d_out, int out_size, void* d_ws, size_t ws_size,
                              hipStream_t stream) {
  (void)in_sizes; (void)n_in; (void)out_size; (void)ws_size;
  const float* stim = (const float*)d_in[0];   // (4,2048,4096)
  const float* init = (const float*)d_in[1];   // (4,250)
  const float* spat = (const float*)d_in[2];   // (2048)
  const float* tcf  = (const float*)d_in[3];   // (250)
  const float* fbf  = (const float*)d_in[4];   // (250)
  const float* bias = (const float*)d_in[5];   // (1)
  float* out = (float*)d_out;                  // (4,64,4096)
  float* sp     = (float*)d_ws;                // 16384 floats
  float* gensig = sp + 16384;                  // 15388 floats

  hipLaunchKernelGGL(k_sp,   dim3(256), dim3(64), 0, stream, stim, spat, sp);
  hipLaunchKernelGGL(k_conv, dim3(241), dim3(64), 0, stream, sp, tcf, bias, gensig);
  hipLaunchKernelGGL(k_sim,  dim3(256), dim3(64), 0, stream, gensig, init, fbf, out);
}

// Round 5
// 412.564 us; speedup vs baseline: 1.5201x; 1.5201x over previous
//
#include <hip/hip_runtime.h>
#include <stdint.h>

// ============================================================================
// CTSimFBOnlyGLM — bit-exact replication of the JAX reference (XLA:CPU
// semantics) including the threefry2x32 PRNG chain.
//
// Validated R1-R4 (absmax 0.0): threefry-partitionable RNG; sequential-p
// spatial proj (mul+add); Eigen predux8 conv; ascending-k gated feedback;
// logit-threshold fast path (theta=logit(u), band) -> exact ladder slow path.
//
// R5 (perf only; decisions provably identical):
//  * k_sim: branchless 64-step chunk body, pure-VALU serial chain:
//      v_readlane(dlt,i literal) -> v_cmp(uniform) -> v_cndmask sf -> v_fma.
//    Band violations accumulate into a sticky `viol`; chunk replayed from a
//    register checkpoint with the R3-validated exact loop iff viol != 0
//    (P ~ 1e-3/chunk). Before the first in-band step fast==replay bitwise,
//    so detection is exact; replay is authoritative for the whole chunk.
//  * R4's 2-step speculation and global_load_lds staging reverted (measured
//    regressions).
//  * k_sp: ping-pong register pipeline (2 x 32 rows, per-element refill
//    interleaved with consumption) -> 32-64 plain global loads in flight,
//    strict sequential-p accumulation unchanged.
// ============================================================================

#pragma clang fp contract(off)

#define TF_ROUND(r) do { x0 += x1; x1 = (x1 << (r)) | (x1 >> (32 - (r))); x1 ^= x0; } while (0)

__device__ __forceinline__ void tf2x32(uint32_t k0, uint32_t k1,
                                       uint32_t x0, uint32_t x1,
                                       uint32_t& o0, uint32_t& o1) {
  const uint32_t k2 = k0 ^ k1 ^ 0x1BD11BDAu;
  x0 += k0; x1 += k1;
  TF_ROUND(13); TF_ROUND(15); TF_ROUND(26); TF_ROUND(6);
  x0 += k1; x1 += k2 + 1u;
  TF_ROUND(17); TF_ROUND(29); TF_ROUND(16); TF_ROUND(24);
  x0 += k2; x1 += k0 + 2u;
  TF_ROUND(13); TF_ROUND(15); TF_ROUND(26); TF_ROUND(6);
  x0 += k0; x1 += k1 + 3u;
  TF_ROUND(17); TF_ROUND(29); TF_ROUND(16); TF_ROUND(24);
  x0 += k1; x1 += k2 + 4u;
  TF_ROUND(13); TF_ROUND(15); TF_ROUND(26); TF_ROUND(6);
  x0 += k2; x1 += k0 + 5u;
  o0 = x0; o1 = x1;
}

// Cephes/Eigen-style f32 exp as XLA's GenerateVF32Exp emits it.
__device__ __forceinline__ float xla_exp_f32(float x) {
  #pragma clang fp contract(off)
  x = fminf(x, 88.3762626647950f);
  x = fmaxf(x, -88.3762626647949f);
  float fx = x * 1.44269504088896341f + 0.5f;
  fx = floorf(fx);
  const float tmp = fx * 0.693359375f;
  const float z0  = fx * (-2.12194440e-4f);
  x = x - tmp;
  x = x - z0;
  const float zz = x * x;
  float y = 1.9875691500e-4f;
  y = y * x + 1.3981999507e-3f;
  y = y * x + 8.3334519073e-3f;
  y = y * x + 4.1665795894e-2f;
  y = y * x + 1.6666665459e-1f;
  y = y * x + 5.0000001201e-1f;
  y = y * zz + x;
  y = y + 1.0f;
  const int n = (int)fx;
  const float p2n = __uint_as_float((uint32_t)(n + 127) << 23);
  return y * p2n;
}

__device__ __forceinline__ float xla_sigmoid_f32(float x) {
  #pragma clang fp contract(off)
  const float e = xla_exp_f32(-x);
  return 1.0f / (1.0f + e);
}

__device__ __forceinline__ float rl_f(float v, int i) {
  return __uint_as_float((uint32_t)__builtin_amdgcn_readlane((int)__float_as_uint(v), i));
}

// Exact reference decision ladder (R1-validated). x = fl(g + fb).
__device__ __forceinline__ uint32_t ladder(float x, float u) {
  #pragma clang fp contract(off)
  const float ef = __expf(-x);
  const float rf = __builtin_amdgcn_rcpf(1.0f + ef);
  const float d2 = u - rf;
  if (fabsf(d2) > 2e-6f) return (d2 < 0.f) ? 1u : 0u;
  const double sd = 1.0 / (1.0 + exp(-(double)x));
  const double dd = (double)u - sd;
  if (fabs(dd) > 5e-7) return (dd < 0.0) ? 1u : 0u;
  return (u < xla_sigmoid_f32(x)) ? 1u : 0u;
}

// ---------------------------------------------------------------------------
// Kernel 1: sp[b,t] = sum_p w[p]*stim[b,p,t]   (strict sequential p, mul+add)
// Ping-pong register pipeline: two 32-row register buffers; each element is
// refilled (rows +64 ahead) immediately after consumption, so 32-64 global
// loads stay in flight with precise compiler vmcnt. Order: ascending p.
// ---------------------------------------------------------------------------
__global__ __launch_bounds__(64) void k_sp(const float* __restrict__ stim,
                                           const float* __restrict__ w,
                                           float* __restrict__ sp) {
  #pragma clang fp contract(off)
  __shared__ float w_lds[2048];
  const int lane = threadIdx.x;
  const int blk  = blockIdx.x;              // 0..255
  const int b  = blk >> 6;
  const int t0 = (blk & 63) * 64;
  for (int j = lane; j < 2048; j += 64) w_lds[j] = w[j];
  __syncthreads();

  const float* __restrict__ gb = stim + (size_t)b * (2048u * 4096u) + t0 + lane;

  float A[32], B[32];
  #pragma unroll
  for (int k = 0; k < 32; ++k) A[k] = gb[(size_t)k * 4096];
  #pragma unroll
  for (int k = 0; k < 32; ++k) B[k] = gb[(size_t)(32 + k) * 4096];

  float acc = 0.f;
  for (int s = 0; s < 32; ++s) {            // rows 64s .. 64s+63
    const int pa = 64 * s;
    #pragma unroll
    for (int k = 0; k < 32; ++k) {
      acc = acc + w_lds[pa + k] * A[k];
      if (s < 31) A[k] = gb[(size_t)(pa + 64 + k) * 4096];
    }
    #pragma unroll
    for (int k = 0; k < 32; ++k) {
      acc = acc + w_lds[pa + 32 + k] * B[k];
      if (s < 31) B[k] = gb[(size_t)(pa + 96 + k) * 4096];
    }
  }
  sp[blk * 64 + lane] = acc;
}

// ---------------------------------------------------------------------------
// Kernel 2: gensig[b,l] = conv_valid(sp, tc)[b,l] + bias
// Eigen RowMajor gemv model: 8 partials (mul+add), predux8 tree, 2 tails.
// ---------------------------------------------------------------------------
__global__ __launch_bounds__(64) void k_conv(const float* __restrict__ sp,
                                             const float* __restrict__ tc,
                                             const float* __restrict__ bias,
                                             float* __restrict__ gensig) {
  #pragma clang fp contract(off)
  const int tid = blockIdx.x * 64 + threadIdx.x;
  if (tid >= 4 * 3847) return;
  const int b = tid / 3847;
  const int l = tid - b * 3847;
  const float* __restrict__ s = sp + b * 4096 + l;
  float a[8];
  #pragma unroll
  for (int j = 0; j < 8; ++j) a[j] = 0.f;
  for (int c = 0; c < 31; ++c) {
    const int k = c * 8;
    #pragma unroll
    for (int j = 0; j < 8; ++j) a[j] = a[j] + s[k + j] * tc[k + j];
  }
  const float b0 = a[0] + a[4];
  const float b1 = a[1] + a[5];
  const float b2 = a[2] + a[6];
  const float b3 = a[3] + a[7];
  float cc = (b0 + b2) + (b1 + b3);
  cc = cc + s[248] * tc[248];
  cc = cc + s[249] * tc[249];
  gensig[tid] = cc + bias[0];
}

// ---------------------------------------------------------------------------
// Kernel 3: sequential simulation, one wave per trajectory, ring in VGPRs.
// Fast path: branchless, VALU-only serial chain. Replay path: exact R3 loop
// from a register checkpoint, triggered iff any deciding lane was in-band.
// ---------------------------------------------------------------------------
__global__ __launch_bounds__(64) void k_sim(const float* __restrict__ gensig,
                                            const float* __restrict__ init,
                                            const float* __restrict__ fbf,
                                            float* __restrict__ out) {
  #pragma clang fp contract(off)
  __shared__ float ring[256];
  __shared__ float f_lds[256];
  __shared__ float init_lds[256];
  __shared__ float T[512];
  const int lane = threadIdx.x;
  const int traj = blockIdx.x;        // b*64 + r, flat (4,64) index
  const int b = traj >> 6;

  for (int j = lane; j < 256; j += 64) {
    f_lds[j]    = (j < 250) ? fbf[j] : 0.f;
    init_lds[j] = (j < 250) ? init[b * 250 + j] : 0.f;
    ring[j] = 0.f;
  }
  __syncthreads();

  // Coefficient tables (R3-validated mapping).
  for (int idx = lane; idx < 512; idx += 64) {
    const int j = idx >> 7;
    const int e = (idx & 127) - 64;
    int src;
    if (j == 0) src = (e < 0) ? (250 + e) : (e - 6);
    else        src = 250 - 64 * j + e;
    T[idx] = (src >= 0 && src < 250) ? f_lds[src] : 0.f;
  }

  // Initial-window ring: slot s = sum_{k=0..249-s} init[s+k]*f[k], asc. k.
  for (int s = lane; s < 250; s += 64) {
    float acc = 0.f;
    const int kmax = 249 - s;
    for (int k = 0; k <= kmax; ++k) acc = acc + init_lds[s + k] * f_lds[k];
    ring[s] = acc;
  }
  __syncthreads();

  const size_t ob = (size_t)traj * 4096;
  for (int j = lane; j < 250; j += 64) out[ob + j] = init_lds[j];

  float r0 = ring[lane];
  float r1 = ring[lane + 64];
  float r2 = ring[lane + 128];
  float r3 = ring[lane + 192];

  const float* __restrict__ grow = gensig + b * 3847;
  const float* __restrict__ Tl = &T[64 - lane];

  for (int tb = 0; tb < 3904; tb += 64) {     // 61 chunks; last one padded
    const int tl = tb + lane;
    float vg = 0.f, vu = 0.f, vgt, band;
    if (tl < 3846) {
      vg = grow[tl];
      uint32_t a0, a1, c0, c1;
      tf2x32(0u, 42u, 0u, (uint32_t)tl, a0, a1);      // keys[t] (fold-like split)
      tf2x32(a0, a1, 0u, (uint32_t)traj, c0, c1);     // per-step bits, elem m=traj
      const uint32_t bits = c0 ^ c1;
      vu = __uint_as_float((bits >> 9) | 0x3f800000u) - 1.0f;
      const float om = 1.0f - vu;                     // exact (u has <=23 bits)
      const float th = __log2f(vu / om) * 0.69314718055994531f;
      vgt = vg - th;
      band = 1.5e-5f + 2e-6f / om
           + 3e-7f * (fabsf(th) + fabsf(vg) + fabsf(vgt));
    } else {
      vgt = -INFINITY;                                // padded: never spikes
      band = -1.0f;                                   // and never in band
    }

    // Checkpoint for possible exact replay.
    const float c0r = r0, c1r = r1, c2r = r2, c3r = r3;
    float vspk = 0.f;
    float viol = 0.f;

    // ---- fast branchless body ----
    #define STEP(i)                                                          \
    {                                                                        \
      const float a0 = Tl[(i)];                                              \
      const float a1 = Tl[(i) + 128];                                        \
      const float a2 = Tl[(i) + 256];                                        \
      const float a3 = Tl[(i) + 384];                                        \
      const float dlt = vgt + r0;                                            \
      const float di = rl_f(dlt, (i));                                       \
      const float bi = rl_f(band, (i));                                      \
      const float sf = (di > 0.0f) ? 1.0f : 0.0f;                            \
      viol += (fabsf(di) <= bi) ? 1.0f : 0.0f;                               \
      const bool mine = (lane == (i));                                       \
      r0 = mine ? 0.0f : r0;                                                 \
      vspk = mine ? sf : vspk;                                               \
      r0 = __builtin_fmaf(sf, a0, r0);                                       \
      r1 = __builtin_fmaf(sf, a1, r1);                                       \
      r2 = __builtin_fmaf(sf, a2, r2);                                       \
      r3 = __builtin_fmaf(sf, a3, r3);                                       \
    }
    #define STEP8(base) STEP(base) STEP(base+1) STEP(base+2) STEP(base+3) \
                        STEP(base+4) STEP(base+5) STEP(base+6) STEP(base+7)
    STEP8(0) STEP8(8) STEP8(16) STEP8(24)
    STEP8(32) STEP8(40) STEP8(48) STEP8(56)
    #undef STEP8
    #undef STEP

    // ---- exact replay (R3-validated semantics), ~1e-3 of chunks ----
    if (__builtin_expect(viol != 0.0f, 0)) {
      r0 = c0r; r1 = c1r; r2 = c2r; r3 = c3r;
      vspk = 0.f;
      for (int i = 0; i < 64; ++i) {
        const float a0 = Tl[i];
        const float a1 = Tl[i + 128];
        const float a2 = Tl[i + 256];
        const float a3 = Tl[i + 384];
        const float dlt = vgt + r0;
        const uint64_t ms = __ballot(dlt > 0.0f);
        const uint64_t mb = __ballot(fabsf(dlt) <= band);
        uint32_t spike = (uint32_t)(ms >> i) & 1u;
        if ((mb >> i) & 1ull) {
          const float x = rl_f(vg, i) + rl_f(r0, i);  // pre-retire r0
          spike = ladder(x, rl_f(vu, i));
        }
        const float sf = spike ? 1.0f : 0.0f;
        const bool mine = (lane == i);
        r0 = mine ? 0.0f : r0;
        vspk = mine ? sf : vspk;
        r0 = __builtin_fmaf(sf, a0, r0);
        r1 = __builtin_fmaf(sf, a1, r1);
        r2 = __builtin_fmaf(sf, a2, r2);
        r3 = __builtin_fmaf(sf, a3, r3);
      }
    }

    if (tl < 3846) out[ob + 250 + tl] = vspk;
    // rotate ring registers for the next 64-step chunk
    const float tmp = r0; r0 = r1; r1 = r2; r2 = r3; r3 = tmp;
  }
}

// ---------------------------------------------------------------------------
extern "C" void kernel_launch(void* const* d_in, const int* in_sizes, int n_in,
                              void* d_out, int out_size, void* d_ws, size_t ws_size,
                              hipStream_t stream) {
  (void)in_sizes; (void)n_in; (void)out_size; (void)ws_size;
  const float* stim = (const float*)d_in[0];   // (4,2048,4096)
  const float* init = (const float*)d_in[1];   // (4,250)
  const float* spat = (const float*)d_in[2];   // (2048)
  const float* tcf  = (const float*)d_in[3];   // (250)
  const float* fbf  = (const float*)d_in[4];   // (250)
  const float* bias = (const float*)d_in[5];   // (1)
  float* out = (float*)d_out;                  // (4,64,4096)
  float* sp     = (float*)d_ws;                // 16384 floats
  float* gensig = sp + 16384;                  // 15388 floats

  hipLaunchKernelGGL(k_sp,   dim3(256), dim3(64), 0, stream, stim, spat, sp);
  hipLaunchKernelGGL(k_conv, dim3(241), dim3(64), 0, stream, sp, tcf, bias, gensig);
  hipLaunchKernelGGL(k_sim,  dim3(256), dim3(64), 0, stream, gensig, init, fbf, out);
}